// Round 10
// baseline (205.710 us; speedup 1.0000x reference)
//
// PointNet++ FP: three_nn + three_interpolate + pointwise MLP(384->256->128)
// Round 18: 40KB LDS -> 4 blocks/CU, single dispatch round. r17 (88us, best):
// Occupancy 52% (48KB -> 3/CU, grid 1024 = 768+256 two rounds) and bank
// conflicts 2.7M->7.07M (stage float4 writes 8-way aliased; phase-3 group
// bases ALL on bank 0 at 128B stride). Fixes:
//  * scan stage -> SoA x/y/z f32 (24KB, drop |q|^2): dist = (p-q)^2 exact
//    f32 (sum of squares, selection-exact class as r10's form). Granule
//    swizzle swz(G)=G^((G>>2)&3) (involution) spreads phase-3 group bases
//    across banks; SoA write = 3 b128 natural-spread; uniform scan = 6
//    b128 broadcasts/group (was 8).
//  * MLP region 32KB: gather stages interp-only Xs[64][256]; L1 = kk0..7
//    from Xs -> bar -> stage skip[64][128]bf16 (16KB over dead Xs half,
//    row-XOR swizzled) -> bar -> kk8..11. Skip stays LDS-staged => VGPR
//    profile unchanged (no r11 spill repeat). Y1 overlay as before.
//  * LDS max = 40KB (scan 16+24; MLP 32) -> 4 blocks/CU = 32 waves/CU,
//    grid 1024 co-resident in ONE round. __launch_bounds__(512,8): natural
//    pressure ~40 VGPR, cap 64 is headroom not a squeeze.
// SPILL TRIPWIRE: WRITE_SIZE must stay ~40MB; >50MB = scratch -> revert.
// Online-hierarchical scan (r15-r17, verified): per 8-cand group fmin tree
// -> (gmin,gid) insert; exact rescan of 3 winning groups (superset theorem).
// MFMA 16x16x32 bf16 layouts (learn_hip m89/m120 verified):
//   A: [m=lane&15][k=(lane>>4)*8+j]   B: [k=(lane>>4)*8+j][n=lane&15]
//   D: [row=(lane>>4)*4+reg][col=lane&15]
#include <hip/hip_runtime.h>

typedef __bf16 bf16_t;
typedef bf16_t bf16x2_t __attribute__((ext_vector_type(2)));
typedef bf16_t bf16x4_t __attribute__((ext_vector_type(4)));
typedef bf16_t bf16x8_t __attribute__((ext_vector_type(8)));
typedef float floatx4_t __attribute__((ext_vector_type(4)));

constexpr int B_ = 8, N_ = 8192, M_ = 2048;
constexpr int C1 = 128, C2 = 256;
constexpr int K1 = 384, N1 = 256, N2 = 128;

// ws layout (bytes)
constexpr size_t WS_W1T   = 0;         // bf16  [256][384]  = 196608 B
constexpr size_t WS_W2T   = 196608;    // bf16  [128][256]  =  65536 B
constexpr size_t WS_XYZ2P = 262144;    // float4[8*2048]    = 262144 B

// ---------------------------------------------------------------- prep ----
__global__ __launch_bounds__(256) void prep_kernel(
    const float* __restrict__ W1, const float* __restrict__ W2,
    const float* __restrict__ xyz2,
    bf16_t* __restrict__ W1T, bf16_t* __restrict__ W2T,
    float4* __restrict__ xyz2p) {
  int bid = blockIdx.x, tid = threadIdx.x;
  if (bid < 384) {                       // W1 [384][256] -> W1T [256][384]
    int t = bid * 256 + tid;             // 98304 elems
    int n = t / K1, k = t - n * K1;
    W1T[t] = (bf16_t)W1[k * N1 + n];
  } else if (bid < 512) {                // W2 [256][128] -> W2T [128][256]
    int t = (bid - 384) * 256 + tid;     // 32768 elems
    int n = t / N1, k = t - n * N1;
    W2T[t] = (bf16_t)W2[k * N2 + n];
  } else {                               // xyz2 -> float4{x,y,z,0}
    int t = (bid - 512) * 256 + tid;     // 16384 elems
    const float* p = xyz2 + (size_t)t * 3;
    xyz2p[t] = make_float4(p[0], p[1], p[2], 0.0f);
  }
}

// ---------------------------------------------- fused nn+interp+MLP -------
// 1024 blocks x 512 threads; block owns 64 points of batch b = bi&7 (XCD-local
// points2/xyz2p in that XCD's L2). Wave w = candidate chunk of 256.
__global__ __launch_bounds__(512, 8) void fp_fused_kernel(
    const float* __restrict__ xyz1, const float4* __restrict__ xyz2p,
    const float* __restrict__ points1, const float* __restrict__ points2,
    const bf16_t* __restrict__ W1T, const float* __restrict__ b1,
    const bf16_t* __restrict__ W2T, const float* __restrict__ b2,
    float* __restrict__ out) {
  // LDS map (40KB):
  //  scan : sdv [0,8K) siv [8K,16K) | SoA x [16K,24K) y [24K,32K) z [32K,40K)
  //  mlp  : Xs_interp [64][256] bf16 swz [0,32K); skip [64][128] bf16 swz
  //         [0,16K) after L1a; Y1 [64][256] bf16 swz [0,32K)
  __shared__ __align__(16) char smem[40960];

  int bi = blockIdx.x;
  int b = bi & 7;                  // batch -> XCD (round-robin)
  int base = (bi >> 3) * 64;       // tile within batch (0..127)
  int tid = threadIdx.x;
  int wave = __builtin_amdgcn_readfirstlane(tid >> 6);  // 0..7
  int lane = tid & 63;
  size_t bN = (size_t)b * N_ + base;

  float4* sdv = (float4*)smem;             // [8][64] top-3 true d2
  int4*   siv = (int4*)(smem + 8192);      // [8][64] top-3 indices
  float*  sx  = (float*)(smem + 16384);    // [2048] granule-swizzled
  float*  sy  = (float*)(smem + 24576);
  float*  sz  = (float*)(smem + 32768);

  float w0, w1, w2;                // blend weights (lane = point)
  int   i0, i1, i2;                // top-3 indices (lane = point)

  // ===== Stage xyz2 -> SoA LDS (24KB). Thread t owns granule t (cands
  // 4t..4t+3); 64B coalesced global read; granule-swizzled b128 writes. ====
  {
    const float4* src = xyz2p + b * M_;
    float4 c0 = src[tid * 4 + 0], c1 = src[tid * 4 + 1];
    float4 c2 = src[tid * 4 + 2], c3 = src[tid * 4 + 3];
    int s = tid ^ ((tid >> 2) & 3);
    *(float4*)(sx + s * 4) = make_float4(c0.x, c1.x, c2.x, c3.x);
    *(float4*)(sy + s * 4) = make_float4(c0.y, c1.y, c2.y, c3.y);
    *(float4*)(sz + s * 4) = make_float4(c0.z, c1.z, c2.z, c3.z);
  }
  __syncthreads();

  // ===== Phase S: three_nn, online-hierarchical, SoA-LDS-fed ==============
  // wave = chunk of 256 cands (groups wave*32..wave*32+31), lane = point.
  {
    const float* p1 = xyz1 + (bN + lane) * 3;
    float px = p1[0], py = p1[1], pz = p1[2];

    auto dist3 = [&](float qx, float qy, float qz) {
      float dx = px - qx, dy = py - qy, dz = pz - qz;
      return fmaf(dz, dz, fmaf(dy, dy, dx * dx));
    };

    // top-3 group-mins (6 regs)
    float t0 = 1e30f, t1 = 1e30f, t2 = 1e30f;
    int   g0 = 0, g1 = 0, g2 = 0;
    auto insG = [&](float d, int g) {       // branchless, strict <
      bool l0 = d < t0, l1 = d < t1, l2 = d < t2;
      float n0 = fminf(t0, d);
      float n1 = __builtin_amdgcn_fmed3f(d, t0, t1);
      float n2 = __builtin_amdgcn_fmed3f(d, t1, t2);
      int u1 = l0 ? g0 : g;
      int u2 = l1 ? g1 : g;
      g0 = l0 ? g : g0;
      g1 = l1 ? u1 : g1;
      g2 = l2 ? u2 : g2;
      t0 = n0; t1 = n1; t2 = n2;
    };

    int gw = wave << 5;                     // first global group of chunk
#pragma unroll 1
    for (int g = 0; g < 32; ++g) {
      int G0 = (gw + g) << 1;
      int sA = G0 ^ ((G0 >> 2) & 3);
      int G1 = G0 + 1;
      int sB = G1 ^ ((G1 >> 2) & 3);
      float4 xa = *(float4*)(sx + sA * 4), xb = *(float4*)(sx + sB * 4);
      float4 ya = *(float4*)(sy + sA * 4), yb = *(float4*)(sy + sB * 4);
      float4 za = *(float4*)(sz + sA * 4), zb = *(float4*)(sz + sB * 4);
      float d0 = dist3(xa.x, ya.x, za.x), d1 = dist3(xa.y, ya.y, za.y);
      float d2 = dist3(xa.z, ya.z, za.z), d3 = dist3(xa.w, ya.w, za.w);
      float d4 = dist3(xb.x, yb.x, zb.x), d5 = dist3(xb.y, yb.y, zb.y);
      float d6 = dist3(xb.z, yb.z, zb.z), d7 = dist3(xb.w, yb.w, zb.w);
      float gm = fminf(fminf(fminf(d0, d1), fminf(d2, d3)),
                       fminf(fminf(d4, d5), fminf(d6, d7)));
      insG(gm, g);
    }

    // sort winning (local) groups ascending: ref tie-break order
    int ga = min(g0, min(g1, g2));
    int gc = max(g0, max(g1, g2));
    int gb = g0 + g1 + g2 - ga - gc;

    // ---- Phase 3: exact rescan of the 3 winning groups (24 cands) ----
    float s0 = 1e30f, s1 = 1e30f, s2 = 1e30f;
    int   a0 = 0, a1 = 0, a2 = 0;
    auto procIdx = [&](float d, int jj) {
      bool l0 = d < s0, l1 = d < s1, l2 = d < s2;
      float n0v = fminf(s0, d);
      float n1v = __builtin_amdgcn_fmed3f(d, s0, s1);
      float n2v = __builtin_amdgcn_fmed3f(d, s1, s2);
      int u1 = l0 ? a0 : jj;               // carry into slot1
      int u2 = l1 ? a1 : jj;               // carry into slot2
      a0 = l0 ? jj : a0;
      a1 = l1 ? u1 : a1;
      a2 = l2 ? u2 : a2;
      s0 = n0v; s1 = n1v; s2 = n2v;
    };
    auto scanGroup = [&](int gg) {          // per-lane divergent LDS reads
      int G0 = (gw + gg) << 1;
      int sA = G0 ^ ((G0 >> 2) & 3);
      int G1 = G0 + 1;
      int sB = G1 ^ ((G1 >> 2) & 3);
      float4 xa = *(float4*)(sx + sA * 4), xb = *(float4*)(sx + sB * 4);
      float4 ya = *(float4*)(sy + sA * 4), yb = *(float4*)(sy + sB * 4);
      float4 za = *(float4*)(sz + sA * 4), zb = *(float4*)(sz + sB * 4);
      int j8 = (gw + gg) << 3;              // global candidate base
      procIdx(dist3(xa.x, ya.x, za.x), j8 + 0);
      procIdx(dist3(xa.y, ya.y, za.y), j8 + 1);
      procIdx(dist3(xa.z, ya.z, za.z), j8 + 2);
      procIdx(dist3(xa.w, ya.w, za.w), j8 + 3);
      procIdx(dist3(xb.x, yb.x, zb.x), j8 + 4);
      procIdx(dist3(xb.y, yb.y, zb.y), j8 + 5);
      procIdx(dist3(xb.z, yb.z, zb.z), j8 + 6);
      procIdx(dist3(xb.w, yb.w, zb.w), j8 + 7);
    };
    scanGroup(ga); scanGroup(gb); scanGroup(gc);

    sdv[wave * 64 + lane] = make_float4(s0, s1, s2, 0.0f);
    siv[wave * 64 + lane] = make_int4(a0, a1, a2, 0);
  }
  __syncthreads();

  // ===== Fold: every lane folds its point's 8 chunk-partials (redundant
  // across waves -> no serialization; stored d2 is true distance). ========
  {
    float4 d0 = sdv[lane];  int4 x0 = siv[lane];
    float t0 = d0.x, t1 = d0.y, t2 = d0.z;
    int   a0 = x0.x, a1 = x0.y, a2 = x0.z;
    auto ins = [&](float d, int j) {
      if (d < t2) {
        if (d < t1) {
          t2 = t1; a2 = a1;
          if (d < t0) { t1 = t0; a1 = a0; t0 = d; a0 = j; }
          else        { t1 = d;  a1 = j; }
        } else { t2 = d; a2 = j; }
      }
    };
#pragma unroll
    for (int c = 1; c < 8; ++c) {
      float4 dd = sdv[c * 64 + lane];  int4 xx = siv[c * 64 + lane];
      ins(dd.x, xx.x); ins(dd.y, xx.y); ins(dd.z, xx.z);
    }
    float e0 = fmaxf(t0, 1e-10f), e1 = fmaxf(t1, 1e-10f), e2 = fmaxf(t2, 1e-10f);
    float r0 = 1.0f / e0, r1 = 1.0f / e1, r2 = 1.0f / e2;
    float rs = 1.0f / (r0 + r1 + r2);
    w0 = r0 * rs; w1 = r1 * rs; w2 = r2 * rs;
    i0 = a0; i1 = a1; i2 = a2;
  }
  __syncthreads();   // scan regions dead; Xs_interp about to overlay

  // ===== Phase A: gather -> Xs_interp [64][256] bf16 swizzled =============
#pragma unroll 2
  for (int i = 0; i < 8; ++i) {
    int p = wave * 8 + i;
    int j0 = __shfl(i0, p), j1 = __shfl(i1, p), j2 = __shfl(i2, p);
    float u0 = __shfl(w0, p), u1 = __shfl(w1, p), u2 = __shfl(w2, p);
    const float* g0 = points2 + ((size_t)b * M_ + j0) * C2 + lane * 4;
    const float* g1 = points2 + ((size_t)b * M_ + j1) * C2 + lane * 4;
    const float* g2 = points2 + ((size_t)b * M_ + j2) * C2 + lane * 4;
    float4 a0 = *(const float4*)g0;
    float4 a1 = *(const float4*)g1;
    float4 a2 = *(const float4*)g2;
    bf16x4_t v;
    v[0] = (bf16_t)(u0 * a0.x + u1 * a1.x + u2 * a2.x);
    v[1] = (bf16_t)(u0 * a0.y + u1 * a1.y + u2 * a2.y);
    v[2] = (bf16_t)(u0 * a0.z + u1 * a1.z + u2 * a2.z);
    v[3] = (bf16_t)(u0 * a0.w + u1 * a1.w + u2 * a2.w);
    int off = (p << 9) + ((lane * 8) ^ (i << 4));     // (p&7)==i
    *(bf16x4_t*)(smem + off) = v;
  }
  __syncthreads();

  int q = lane >> 4, r = lane & 15;
  int rs8 = (r & 7) << 4;            // row-swizzle XOR (rows r,16+r,32+r,48+r)

  // ---- Layer 1a: interp K=0..255 from Xs_interp; wave owns 32 cols
  floatx4_t acc[4][2] = {};
  int cw = wave * 32;
  const bf16_t* wq0 = W1T + (size_t)(cw +      r) * K1;
  const bf16_t* wq1 = W1T + (size_t)(cw + 16 + r) * K1;
  for (int kk = 0; kk < 8; ++kk) {
    int k0 = kk * 32 + q * 8;
    int co = (k0 << 1) ^ rs8;
    bf16x8_t a0 = *(const bf16x8_t*)(smem + ((     r) << 9) + co);
    bf16x8_t a1 = *(const bf16x8_t*)(smem + ((16 + r) << 9) + co);
    bf16x8_t a2 = *(const bf16x8_t*)(smem + ((32 + r) << 9) + co);
    bf16x8_t a3 = *(const bf16x8_t*)(smem + ((48 + r) << 9) + co);
    bf16x8_t bb0 = *(const bf16x8_t*)(wq0 + k0);
    bf16x8_t bb1 = *(const bf16x8_t*)(wq1 + k0);
    acc[0][0] = __builtin_amdgcn_mfma_f32_16x16x32_bf16(a0, bb0, acc[0][0], 0, 0, 0);
    acc[1][0] = __builtin_amdgcn_mfma_f32_16x16x32_bf16(a1, bb0, acc[1][0], 0, 0, 0);
    acc[2][0] = __builtin_amdgcn_mfma_f32_16x16x32_bf16(a2, bb0, acc[2][0], 0, 0, 0);
    acc[3][0] = __builtin_amdgcn_mfma_f32_16x16x32_bf16(a3, bb0, acc[3][0], 0, 0, 0);
    acc[0][1] = __builtin_amdgcn_mfma_f32_16x16x32_bf16(a0, bb1, acc[0][1], 0, 0, 0);
    acc[1][1] = __builtin_amdgcn_mfma_f32_16x16x32_bf16(a1, bb1, acc[1][1], 0, 0, 0);
    acc[2][1] = __builtin_amdgcn_mfma_f32_16x16x32_bf16(a2, bb1, acc[2][1], 0, 0, 0);
    acc[3][1] = __builtin_amdgcn_mfma_f32_16x16x32_bf16(a3, bb1, acc[3][1], 0, 0, 0);
  }
  __syncthreads();   // all waves done with Xs_interp[0,16K)

  // ---- stage skip: points1 -> [64][128] bf16 @ [0,16K), 256B rows, swz
#pragma unroll 2
  for (int t = 0; t < 8; ++t) {
    int e = tid + t * 512;                  // 0..4095
    int row = e >> 6, pair = e & 63;        // 64 rows x 64 float2
    float2 s = *(const float2*)(points1 + (bN + row) * C1 + pair * 2);
    bf16x2_t v2; v2[0] = (bf16_t)s.x; v2[1] = (bf16_t)s.y;
    int off = (row << 8) + ((pair << 2) ^ ((row & 7) << 4));
    *(bf16x2_t*)(smem + off) = v2;
  }
  __syncthreads();

  // ---- Layer 1b: skip K=256..383 from skip buffer
  for (int kk2 = 0; kk2 < 4; ++kk2) {
    int l = kk2 * 32 + q * 8;               // local col 0..127
    int co = (l << 1) ^ rs8;
    bf16x8_t a0 = *(const bf16x8_t*)(smem + ((     r) << 8) + co);
    bf16x8_t a1 = *(const bf16x8_t*)(smem + ((16 + r) << 8) + co);
    bf16x8_t a2 = *(const bf16x8_t*)(smem + ((32 + r) << 8) + co);
    bf16x8_t a3 = *(const bf16x8_t*)(smem + ((48 + r) << 8) + co);
    int k0 = 256 + l;
    bf16x8_t bb0 = *(const bf16x8_t*)(wq0 + k0);
    bf16x8_t bb1 = *(const bf16x8_t*)(wq1 + k0);
    acc[0][0] = __builtin_amdgcn_mfma_f32_16x16x32_bf16(a0, bb0, acc[0][0], 0, 0, 0);
    acc[1][0] = __builtin_amdgcn_mfma_f32_16x16x32_bf16(a1, bb0, acc[1][0], 0, 0, 0);
    acc[2][0] = __builtin_amdgcn_mfma_f32_16x16x32_bf16(a2, bb0, acc[2][0], 0, 0, 0);
    acc[3][0] = __builtin_amdgcn_mfma_f32_16x16x32_bf16(a3, bb0, acc[3][0], 0, 0, 0);
    acc[0][1] = __builtin_amdgcn_mfma_f32_16x16x32_bf16(a0, bb1, acc[0][1], 0, 0, 0);
    acc[1][1] = __builtin_amdgcn_mfma_f32_16x16x32_bf16(a1, bb1, acc[1][1], 0, 0, 0);
    acc[2][1] = __builtin_amdgcn_mfma_f32_16x16x32_bf16(a2, bb1, acc[2][1], 0, 0, 0);
    acc[3][1] = __builtin_amdgcn_mfma_f32_16x16x32_bf16(a3, bb1, acc[3][1], 0, 0, 0);
  }
  __syncthreads();   // skip region dead only when ALL waves finished L1b

  // bias + relu -> Y1 [64][256] bf16 @ [0,32K), 512B rows, same swizzle
#pragma unroll
  for (int ct = 0; ct < 2; ++ct) {
    int nn = cw + ct * 16 + r;
    float bias = b1[nn];
#pragma unroll
    for (int mt = 0; mt < 4; ++mt) {
#pragma unroll
      for (int reg = 0; reg < 4; ++reg) {
        int m = mt * 16 + q * 4 + reg;
        int off = (m << 9) + ((nn << 1) ^ ((m & 7) << 4));
        *(bf16_t*)(smem + off) = (bf16_t)fmaxf(acc[mt][ct][reg] + bias, 0.0f);
      }
    }
  }
  __syncthreads();

  // ---- Layer 2: [64 x 256] x [256 x 128] -> out, wave owns 16 cols
  floatx4_t acc2[4] = {};
  const bf16_t* vq = W2T + (size_t)(wave * 16 + r) * N1;
  for (int kk = 0; kk < 8; ++kk) {
    int k0 = kk * 32 + q * 8;
    int co = (k0 << 1) ^ rs8;
    bf16x8_t a0 = *(const bf16x8_t*)(smem + ((     r) << 9) + co);
    bf16x8_t a1 = *(const bf16x8_t*)(smem + ((16 + r) << 9) + co);
    bf16x8_t a2 = *(const bf16x8_t*)(smem + ((32 + r) << 9) + co);
    bf16x8_t a3 = *(const bf16x8_t*)(smem + ((48 + r) << 9) + co);
    bf16x8_t bb = *(const bf16x8_t*)(vq + k0);
    acc2[0] = __builtin_amdgcn_mfma_f32_16x16x32_bf16(a0, bb, acc2[0], 0, 0, 0);
    acc2[1] = __builtin_amdgcn_mfma_f32_16x16x32_bf16(a1, bb, acc2[1], 0, 0, 0);
    acc2[2] = __builtin_amdgcn_mfma_f32_16x16x32_bf16(a2, bb, acc2[2], 0, 0, 0);
    acc2[3] = __builtin_amdgcn_mfma_f32_16x16x32_bf16(a3, bb, acc2[3], 0, 0, 0);
  }
  {
    int cc = wave * 16 + r;
    float bias = b2[cc];
#pragma unroll
    for (int mt = 0; mt < 4; ++mt) {
#pragma unroll
      for (int reg = 0; reg < 4; ++reg) {
        int m = mt * 16 + q * 4 + reg;
        out[(bN + m) * N2 + cc] = fmaxf(acc2[mt][reg] + bias, 0.0f);
      }
    }
  }
}

// ----------------------------------------------------------------- launch --
extern "C" void kernel_launch(void* const* d_in, const int* in_sizes, int n_in,
                              void* d_out, int out_size, void* d_ws, size_t ws_size,
                              hipStream_t stream) {
  (void)in_sizes; (void)n_in; (void)out_size; (void)ws_size;
  const float* xyz1    = (const float*)d_in[0];
  const float* xyz2    = (const float*)d_in[1];
  const float* points1 = (const float*)d_in[2];
  const float* points2 = (const float*)d_in[3];
  const float* W1      = (const float*)d_in[4];
  const float* b1      = (const float*)d_in[5];
  const float* W2      = (const float*)d_in[6];
  const float* b2      = (const float*)d_in[7];
  float* out = (float*)d_out;
  char* ws = (char*)d_ws;
  bf16_t* W1T   = (bf16_t*)(ws + WS_W1T);
  bf16_t* W2T   = (bf16_t*)(ws + WS_W2T);
  float4* xyz2p = (float4*)(ws + WS_XYZ2P);

  prep_kernel<<<576, 256, 0, stream>>>(W1, W2, xyz2, W1T, W2T, xyz2p);
  fp_fused_kernel<<<1024, 512, 0, stream>>>(xyz1, xyz2p, points1, points2,
                                            W1T, b1, W2T, b2, out);
}

// Round 11
// 179.796 us; speedup vs baseline: 1.1441x; 1.1441x over previous
//
// PointNet++ FP: three_nn + three_interpolate + pointwise MLP(384->256->128)
// Round 19: r18 structure + __launch_bounds__(512,6). r18 post-mortem:
// (512,8) -> VGPR=32 + catastrophic spills (FETCH 87MB, WRITE 130MB), same
// signature as r11. EMPIRICAL RULE (2x confirmed): (512,8) squeezes the
// allocator to 32 VGPR and spills; (512,6) lands ~40-56 VGPR, zero scratch
// (r12-r17). r18's structural changes were healthy underneath: occupancy
// 70% (4 blocks/CU resident), conflicts 7.07M -> 3.66M. Keep them:
//  * SoA scan stage x/y/z f32 24KB, granule swizzle G^((G>>2)&3);
//    dist=(p-q)^2 exact f32.
//  * MLP region 32KB: Xs_interp[64][256] -> L1a -> stage skip[64][128]
//    over dead half -> L1b; Y1 overlay.
//  * LDS 40KB -> 4 blocks/CU (if VGPR<=64), grid 1024 in one round.
// SPILL TRIPWIRE: WRITE_SIZE must stay ~40-42MB; >50MB = scratch -> revert.
// Online-hierarchical scan (r15-r17, verified): per 8-cand group fmin tree
// -> (gmin,gid) insert; exact rescan of 3 winning groups (superset theorem).
// MFMA 16x16x32 bf16 layouts (learn_hip m89/m120 verified):
//   A: [m=lane&15][k=(lane>>4)*8+j]   B: [k=(lane>>4)*8+j][n=lane&15]
//   D: [row=(lane>>4)*4+reg][col=lane&15]
#include <hip/hip_runtime.h>

typedef __bf16 bf16_t;
typedef bf16_t bf16x2_t __attribute__((ext_vector_type(2)));
typedef bf16_t bf16x4_t __attribute__((ext_vector_type(4)));
typedef bf16_t bf16x8_t __attribute__((ext_vector_type(8)));
typedef float floatx4_t __attribute__((ext_vector_type(4)));

constexpr int B_ = 8, N_ = 8192, M_ = 2048;
constexpr int C1 = 128, C2 = 256;
constexpr int K1 = 384, N1 = 256, N2 = 128;

// ws layout (bytes)
constexpr size_t WS_W1T   = 0;         // bf16  [256][384]  = 196608 B
constexpr size_t WS_W2T   = 196608;    // bf16  [128][256]  =  65536 B
constexpr size_t WS_XYZ2P = 262144;    // float4[8*2048]    = 262144 B

// ---------------------------------------------------------------- prep ----
__global__ __launch_bounds__(256) void prep_kernel(
    const float* __restrict__ W1, const float* __restrict__ W2,
    const float* __restrict__ xyz2,
    bf16_t* __restrict__ W1T, bf16_t* __restrict__ W2T,
    float4* __restrict__ xyz2p) {
  int bid = blockIdx.x, tid = threadIdx.x;
  if (bid < 384) {                       // W1 [384][256] -> W1T [256][384]
    int t = bid * 256 + tid;             // 98304 elems
    int n = t / K1, k = t - n * K1;
    W1T[t] = (bf16_t)W1[k * N1 + n];
  } else if (bid < 512) {                // W2 [256][128] -> W2T [128][256]
    int t = (bid - 384) * 256 + tid;     // 32768 elems
    int n = t / N1, k = t - n * N1;
    W2T[t] = (bf16_t)W2[k * N2 + n];
  } else {                               // xyz2 -> float4{x,y,z,0}
    int t = (bid - 512) * 256 + tid;     // 16384 elems
    const float* p = xyz2 + (size_t)t * 3;
    xyz2p[t] = make_float4(p[0], p[1], p[2], 0.0f);
  }
}

// ---------------------------------------------- fused nn+interp+MLP -------
// 1024 blocks x 512 threads; block owns 64 points of batch b = bi&7 (XCD-local
// points2/xyz2p in that XCD's L2). Wave w = candidate chunk of 256.
__global__ __launch_bounds__(512, 6) void fp_fused_kernel(
    const float* __restrict__ xyz1, const float4* __restrict__ xyz2p,
    const float* __restrict__ points1, const float* __restrict__ points2,
    const bf16_t* __restrict__ W1T, const float* __restrict__ b1,
    const bf16_t* __restrict__ W2T, const float* __restrict__ b2,
    float* __restrict__ out) {
  // LDS map (40KB):
  //  scan : sdv [0,8K) siv [8K,16K) | SoA x [16K,24K) y [24K,32K) z [32K,40K)
  //  mlp  : Xs_interp [64][256] bf16 swz [0,32K); skip [64][128] bf16 swz
  //         [0,16K) after L1a; Y1 [64][256] bf16 swz [0,32K)
  __shared__ __align__(16) char smem[40960];

  int bi = blockIdx.x;
  int b = bi & 7;                  // batch -> XCD (round-robin)
  int base = (bi >> 3) * 64;       // tile within batch (0..127)
  int tid = threadIdx.x;
  int wave = __builtin_amdgcn_readfirstlane(tid >> 6);  // 0..7
  int lane = tid & 63;
  size_t bN = (size_t)b * N_ + base;

  float4* sdv = (float4*)smem;             // [8][64] top-3 true d2
  int4*   siv = (int4*)(smem + 8192);      // [8][64] top-3 indices
  float*  sx  = (float*)(smem + 16384);    // [2048] granule-swizzled
  float*  sy  = (float*)(smem + 24576);
  float*  sz  = (float*)(smem + 32768);

  float w0, w1, w2;                // blend weights (lane = point)
  int   i0, i1, i2;                // top-3 indices (lane = point)

  // ===== Stage xyz2 -> SoA LDS (24KB). Thread t owns granule t (cands
  // 4t..4t+3); 64B coalesced global read; granule-swizzled b128 writes. ====
  {
    const float4* src = xyz2p + b * M_;
    float4 c0 = src[tid * 4 + 0], c1 = src[tid * 4 + 1];
    float4 c2 = src[tid * 4 + 2], c3 = src[tid * 4 + 3];
    int s = tid ^ ((tid >> 2) & 3);
    *(float4*)(sx + s * 4) = make_float4(c0.x, c1.x, c2.x, c3.x);
    *(float4*)(sy + s * 4) = make_float4(c0.y, c1.y, c2.y, c3.y);
    *(float4*)(sz + s * 4) = make_float4(c0.z, c1.z, c2.z, c3.z);
  }
  __syncthreads();

  // ===== Phase S: three_nn, online-hierarchical, SoA-LDS-fed ==============
  // wave = chunk of 256 cands (groups wave*32..wave*32+31), lane = point.
  {
    const float* p1 = xyz1 + (bN + lane) * 3;
    float px = p1[0], py = p1[1], pz = p1[2];

    auto dist3 = [&](float qx, float qy, float qz) {
      float dx = px - qx, dy = py - qy, dz = pz - qz;
      return fmaf(dz, dz, fmaf(dy, dy, dx * dx));
    };

    // top-3 group-mins (6 regs)
    float t0 = 1e30f, t1 = 1e30f, t2 = 1e30f;
    int   g0 = 0, g1 = 0, g2 = 0;
    auto insG = [&](float d, int g) {       // branchless, strict <
      bool l0 = d < t0, l1 = d < t1, l2 = d < t2;
      float n0 = fminf(t0, d);
      float n1 = __builtin_amdgcn_fmed3f(d, t0, t1);
      float n2 = __builtin_amdgcn_fmed3f(d, t1, t2);
      int u1 = l0 ? g0 : g;
      int u2 = l1 ? g1 : g;
      g0 = l0 ? g : g0;
      g1 = l1 ? u1 : g1;
      g2 = l2 ? u2 : g2;
      t0 = n0; t1 = n1; t2 = n2;
    };

    int gw = wave << 5;                     // first global group of chunk
#pragma unroll 1
    for (int g = 0; g < 32; ++g) {
      int G0 = (gw + g) << 1;
      int sA = G0 ^ ((G0 >> 2) & 3);
      int G1 = G0 + 1;
      int sB = G1 ^ ((G1 >> 2) & 3);
      float4 xa = *(float4*)(sx + sA * 4), xb = *(float4*)(sx + sB * 4);
      float4 ya = *(float4*)(sy + sA * 4), yb = *(float4*)(sy + sB * 4);
      float4 za = *(float4*)(sz + sA * 4), zb = *(float4*)(sz + sB * 4);
      float d0 = dist3(xa.x, ya.x, za.x), d1 = dist3(xa.y, ya.y, za.y);
      float d2 = dist3(xa.z, ya.z, za.z), d3 = dist3(xa.w, ya.w, za.w);
      float d4 = dist3(xb.x, yb.x, zb.x), d5 = dist3(xb.y, yb.y, zb.y);
      float d6 = dist3(xb.z, yb.z, zb.z), d7 = dist3(xb.w, yb.w, zb.w);
      float gm = fminf(fminf(fminf(d0, d1), fminf(d2, d3)),
                       fminf(fminf(d4, d5), fminf(d6, d7)));
      insG(gm, g);
    }

    // sort winning (local) groups ascending: ref tie-break order
    int ga = min(g0, min(g1, g2));
    int gc = max(g0, max(g1, g2));
    int gb = g0 + g1 + g2 - ga - gc;

    // ---- Phase 3: exact rescan of the 3 winning groups (24 cands) ----
    float s0 = 1e30f, s1 = 1e30f, s2 = 1e30f;
    int   a0 = 0, a1 = 0, a2 = 0;
    auto procIdx = [&](float d, int jj) {
      bool l0 = d < s0, l1 = d < s1, l2 = d < s2;
      float n0v = fminf(s0, d);
      float n1v = __builtin_amdgcn_fmed3f(d, s0, s1);
      float n2v = __builtin_amdgcn_fmed3f(d, s1, s2);
      int u1 = l0 ? a0 : jj;               // carry into slot1
      int u2 = l1 ? a1 : jj;               // carry into slot2
      a0 = l0 ? jj : a0;
      a1 = l1 ? u1 : a1;
      a2 = l2 ? u2 : a2;
      s0 = n0v; s1 = n1v; s2 = n2v;
    };
    auto scanGroup = [&](int gg) {          // per-lane divergent LDS reads
      int G0 = (gw + gg) << 1;
      int sA = G0 ^ ((G0 >> 2) & 3);
      int G1 = G0 + 1;
      int sB = G1 ^ ((G1 >> 2) & 3);
      float4 xa = *(float4*)(sx + sA * 4), xb = *(float4*)(sx + sB * 4);
      float4 ya = *(float4*)(sy + sA * 4), yb = *(float4*)(sy + sB * 4);
      float4 za = *(float4*)(sz + sA * 4), zb = *(float4*)(sz + sB * 4);
      int j8 = (gw + gg) << 3;              // global candidate base
      procIdx(dist3(xa.x, ya.x, za.x), j8 + 0);
      procIdx(dist3(xa.y, ya.y, za.y), j8 + 1);
      procIdx(dist3(xa.z, ya.z, za.z), j8 + 2);
      procIdx(dist3(xa.w, ya.w, za.w), j8 + 3);
      procIdx(dist3(xb.x, yb.x, zb.x), j8 + 4);
      procIdx(dist3(xb.y, yb.y, zb.y), j8 + 5);
      procIdx(dist3(xb.z, yb.z, zb.z), j8 + 6);
      procIdx(dist3(xb.w, yb.w, zb.w), j8 + 7);
    };
    scanGroup(ga); scanGroup(gb); scanGroup(gc);

    sdv[wave * 64 + lane] = make_float4(s0, s1, s2, 0.0f);
    siv[wave * 64 + lane] = make_int4(a0, a1, a2, 0);
  }
  __syncthreads();

  // ===== Fold: every lane folds its point's 8 chunk-partials (redundant
  // across waves -> no serialization; stored d2 is true distance). ========
  {
    float4 d0 = sdv[lane];  int4 x0 = siv[lane];
    float t0 = d0.x, t1 = d0.y, t2 = d0.z;
    int   a0 = x0.x, a1 = x0.y, a2 = x0.z;
    auto ins = [&](float d, int j) {
      if (d < t2) {
        if (d < t1) {
          t2 = t1; a2 = a1;
          if (d < t0) { t1 = t0; a1 = a0; t0 = d; a0 = j; }
          else        { t1 = d;  a1 = j; }
        } else { t2 = d; a2 = j; }
      }
    };
#pragma unroll
    for (int c = 1; c < 8; ++c) {
      float4 dd = sdv[c * 64 + lane];  int4 xx = siv[c * 64 + lane];
      ins(dd.x, xx.x); ins(dd.y, xx.y); ins(dd.z, xx.z);
    }
    float e0 = fmaxf(t0, 1e-10f), e1 = fmaxf(t1, 1e-10f), e2 = fmaxf(t2, 1e-10f);
    float r0 = 1.0f / e0, r1 = 1.0f / e1, r2 = 1.0f / e2;
    float rs = 1.0f / (r0 + r1 + r2);
    w0 = r0 * rs; w1 = r1 * rs; w2 = r2 * rs;
    i0 = a0; i1 = a1; i2 = a2;
  }
  __syncthreads();   // scan regions dead; Xs_interp about to overlay

  // ===== Phase A: gather -> Xs_interp [64][256] bf16 swizzled =============
#pragma unroll 2
  for (int i = 0; i < 8; ++i) {
    int p = wave * 8 + i;
    int j0 = __shfl(i0, p), j1 = __shfl(i1, p), j2 = __shfl(i2, p);
    float u0 = __shfl(w0, p), u1 = __shfl(w1, p), u2 = __shfl(w2, p);
    const float* g0 = points2 + ((size_t)b * M_ + j0) * C2 + lane * 4;
    const float* g1 = points2 + ((size_t)b * M_ + j1) * C2 + lane * 4;
    const float* g2 = points2 + ((size_t)b * M_ + j2) * C2 + lane * 4;
    float4 a0 = *(const float4*)g0;
    float4 a1 = *(const float4*)g1;
    float4 a2 = *(const float4*)g2;
    bf16x4_t v;
    v[0] = (bf16_t)(u0 * a0.x + u1 * a1.x + u2 * a2.x);
    v[1] = (bf16_t)(u0 * a0.y + u1 * a1.y + u2 * a2.y);
    v[2] = (bf16_t)(u0 * a0.z + u1 * a1.z + u2 * a2.z);
    v[3] = (bf16_t)(u0 * a0.w + u1 * a1.w + u2 * a2.w);
    int off = (p << 9) + ((lane * 8) ^ (i << 4));     // (p&7)==i
    *(bf16x4_t*)(smem + off) = v;
  }
  __syncthreads();

  int q = lane >> 4, r = lane & 15;
  int rs8 = (r & 7) << 4;            // row-swizzle XOR (rows r,16+r,32+r,48+r)

  // ---- Layer 1a: interp K=0..255 from Xs_interp; wave owns 32 cols
  floatx4_t acc[4][2] = {};
  int cw = wave * 32;
  const bf16_t* wq0 = W1T + (size_t)(cw +      r) * K1;
  const bf16_t* wq1 = W1T + (size_t)(cw + 16 + r) * K1;
  for (int kk = 0; kk < 8; ++kk) {
    int k0 = kk * 32 + q * 8;
    int co = (k0 << 1) ^ rs8;
    bf16x8_t a0 = *(const bf16x8_t*)(smem + ((     r) << 9) + co);
    bf16x8_t a1 = *(const bf16x8_t*)(smem + ((16 + r) << 9) + co);
    bf16x8_t a2 = *(const bf16x8_t*)(smem + ((32 + r) << 9) + co);
    bf16x8_t a3 = *(const bf16x8_t*)(smem + ((48 + r) << 9) + co);
    bf16x8_t bb0 = *(const bf16x8_t*)(wq0 + k0);
    bf16x8_t bb1 = *(const bf16x8_t*)(wq1 + k0);
    acc[0][0] = __builtin_amdgcn_mfma_f32_16x16x32_bf16(a0, bb0, acc[0][0], 0, 0, 0);
    acc[1][0] = __builtin_amdgcn_mfma_f32_16x16x32_bf16(a1, bb0, acc[1][0], 0, 0, 0);
    acc[2][0] = __builtin_amdgcn_mfma_f32_16x16x32_bf16(a2, bb0, acc[2][0], 0, 0, 0);
    acc[3][0] = __builtin_amdgcn_mfma_f32_16x16x32_bf16(a3, bb0, acc[3][0], 0, 0, 0);
    acc[0][1] = __builtin_amdgcn_mfma_f32_16x16x32_bf16(a0, bb1, acc[0][1], 0, 0, 0);
    acc[1][1] = __builtin_amdgcn_mfma_f32_16x16x32_bf16(a1, bb1, acc[1][1], 0, 0, 0);
    acc[2][1] = __builtin_amdgcn_mfma_f32_16x16x32_bf16(a2, bb1, acc[2][1], 0, 0, 0);
    acc[3][1] = __builtin_amdgcn_mfma_f32_16x16x32_bf16(a3, bb1, acc[3][1], 0, 0, 0);
  }
  __syncthreads();   // all waves done with Xs_interp[0,16K)

  // ---- stage skip: points1 -> [64][128] bf16 @ [0,16K), 256B rows, swz
#pragma unroll 2
  for (int t = 0; t < 8; ++t) {
    int e = tid + t * 512;                  // 0..4095
    int row = e >> 6, pair = e & 63;        // 64 rows x 64 float2
    float2 s = *(const float2*)(points1 + (bN + row) * C1 + pair * 2);
    bf16x2_t v2; v2[0] = (bf16_t)s.x; v2[1] = (bf16_t)s.y;
    int off = (row << 8) + ((pair << 2) ^ ((row & 7) << 4));
    *(bf16x2_t*)(smem + off) = v2;
  }
  __syncthreads();

  // ---- Layer 1b: skip K=256..383 from skip buffer
  for (int kk2 = 0; kk2 < 4; ++kk2) {
    int l = kk2 * 32 + q * 8;               // local col 0..127
    int co = (l << 1) ^ rs8;
    bf16x8_t a0 = *(const bf16x8_t*)(smem + ((     r) << 8) + co);
    bf16x8_t a1 = *(const bf16x8_t*)(smem + ((16 + r) << 8) + co);
    bf16x8_t a2 = *(const bf16x8_t*)(smem + ((32 + r) << 8) + co);
    bf16x8_t a3 = *(const bf16x8_t*)(smem + ((48 + r) << 8) + co);
    int k0 = 256 + l;
    bf16x8_t bb0 = *(const bf16x8_t*)(wq0 + k0);
    bf16x8_t bb1 = *(const bf16x8_t*)(wq1 + k0);
    acc[0][0] = __builtin_amdgcn_mfma_f32_16x16x32_bf16(a0, bb0, acc[0][0], 0, 0, 0);
    acc[1][0] = __builtin_amdgcn_mfma_f32_16x16x32_bf16(a1, bb0, acc[1][0], 0, 0, 0);
    acc[2][0] = __builtin_amdgcn_mfma_f32_16x16x32_bf16(a2, bb0, acc[2][0], 0, 0, 0);
    acc[3][0] = __builtin_amdgcn_mfma_f32_16x16x32_bf16(a3, bb0, acc[3][0], 0, 0, 0);
    acc[0][1] = __builtin_amdgcn_mfma_f32_16x16x32_bf16(a0, bb1, acc[0][1], 0, 0, 0);
    acc[1][1] = __builtin_amdgcn_mfma_f32_16x16x32_bf16(a1, bb1, acc[1][1], 0, 0, 0);
    acc[2][1] = __builtin_amdgcn_mfma_f32_16x16x32_bf16(a2, bb1, acc[2][1], 0, 0, 0);
    acc[3][1] = __builtin_amdgcn_mfma_f32_16x16x32_bf16(a3, bb1, acc[3][1], 0, 0, 0);
  }
  __syncthreads();   // skip region dead only when ALL waves finished L1b

  // bias + relu -> Y1 [64][256] bf16 @ [0,32K), 512B rows, same swizzle
#pragma unroll
  for (int ct = 0; ct < 2; ++ct) {
    int nn = cw + ct * 16 + r;
    float bias = b1[nn];
#pragma unroll
    for (int mt = 0; mt < 4; ++mt) {
#pragma unroll
      for (int reg = 0; reg < 4; ++reg) {
        int m = mt * 16 + q * 4 + reg;
        int off = (m << 9) + ((nn << 1) ^ ((m & 7) << 4));
        *(bf16_t*)(smem + off) = (bf16_t)fmaxf(acc[mt][ct][reg] + bias, 0.0f);
      }
    }
  }
  __syncthreads();

  // ---- Layer 2: [64 x 256] x [256 x 128] -> out, wave owns 16 cols
  floatx4_t acc2[4] = {};
  const bf16_t* vq = W2T + (size_t)(wave * 16 + r) * N1;
  for (int kk = 0; kk < 8; ++kk) {
    int k0 = kk * 32 + q * 8;
    int co = (k0 << 1) ^ rs8;
    bf16x8_t a0 = *(const bf16x8_t*)(smem + ((     r) << 9) + co);
    bf16x8_t a1 = *(const bf16x8_t*)(smem + ((16 + r) << 9) + co);
    bf16x8_t a2 = *(const bf16x8_t*)(smem + ((32 + r) << 9) + co);
    bf16x8_t a3 = *(const bf16x8_t*)(smem + ((48 + r) << 9) + co);
    bf16x8_t bb = *(const bf16x8_t*)(vq + k0);
    acc2[0] = __builtin_amdgcn_mfma_f32_16x16x32_bf16(a0, bb, acc2[0], 0, 0, 0);
    acc2[1] = __builtin_amdgcn_mfma_f32_16x16x32_bf16(a1, bb, acc2[1], 0, 0, 0);
    acc2[2] = __builtin_amdgcn_mfma_f32_16x16x32_bf16(a2, bb, acc2[2], 0, 0, 0);
    acc2[3] = __builtin_amdgcn_mfma_f32_16x16x32_bf16(a3, bb, acc2[3], 0, 0, 0);
  }
  {
    int cc = wave * 16 + r;
    float bias = b2[cc];
#pragma unroll
    for (int mt = 0; mt < 4; ++mt) {
#pragma unroll
      for (int reg = 0; reg < 4; ++reg) {
        int m = mt * 16 + q * 4 + reg;
        out[(bN + m) * N2 + cc] = fmaxf(acc2[mt][reg] + bias, 0.0f);
      }
    }
  }
}

// ----------------------------------------------------------------- launch --
extern "C" void kernel_launch(void* const* d_in, const int* in_sizes, int n_in,
                              void* d_out, int out_size, void* d_ws, size_t ws_size,
                              hipStream_t stream) {
  (void)in_sizes; (void)n_in; (void)out_size; (void)ws_size;
  const float* xyz1    = (const float*)d_in[0];
  const float* xyz2    = (const float*)d_in[1];
  const float* points1 = (const float*)d_in[2];
  const float* points2 = (const float*)d_in[3];
  const float* W1      = (const float*)d_in[4];
  const float* b1      = (const float*)d_in[5];
  const float* W2      = (const float*)d_in[6];
  const float* b2      = (const float*)d_in[7];
  float* out = (float*)d_out;
  char* ws = (char*)d_ws;
  bf16_t* W1T   = (bf16_t*)(ws + WS_W1T);
  bf16_t* W2T   = (bf16_t*)(ws + WS_W2T);
  float4* xyz2p = (float4*)(ws + WS_XYZ2P);

  prep_kernel<<<576, 256, 0, stream>>>(W1, W2, xyz2, W1T, W2T, xyz2p);
  fp_fused_kernel<<<1024, 512, 0, stream>>>(xyz1, xyz2p, points1, points2,
                                            W1T, b1, W2T, b2, out);
}